// Round 10
// baseline (88.690 us; speedup 1.0000x reference)
//
#include <hip/hip_runtime.h>

// Varifold loss kxx + kyy - 2*kxy via mfma_f32_32x32x16_bf16, three-phase.
// Phase 1 (vf_encode): encode every point once into bf16 MFMA fragments in
//   d_ws (A-form and B-form, S and D matrices), hi/lo-split (~fp24), with
//   -log2(e) folded into S so accS IS the exp2 argument.
// Phase 2 (vf_main): builtin MFMA (R7: raw asm MFMA -> hazard corruption),
//   software-pipelined one tile deep: tile jt+1's MFMAs issue before tile
//   jt's exp2 epilogue, so MFMA latency hides under ~200cyc of trans work.
//   Trans-pipe bound: 16 v_exp_f32 per 1024 pairs. xx/yy on upper-triangle
//   512x512 supertiles, off-diag weight 2 (70.8% of pairs). 16KB LDS, no
//   VGPR cap (R9's 128 cap risked spills with 2 tiles' f32x16 accs live).
//   No same-address atomics (R5: ~10ns serialized memory-side op each).
// Phase 3 (vf_reduce): one block double-sums 4352 partials -> out[0].

typedef short bf16x8 __attribute__((ext_vector_type(8)));
typedef float f32x16 __attribute__((ext_vector_type(16)));
typedef float f32x2  __attribute__((ext_vector_type(2)));

#define NPTS 4096
#define BATCH 4
#define IBLK 128                   // 4 waves x one 32-row i-tile each
#define JCHUNK 256                 // 8 j-tiles of 32
#define LOG2E 1.4426950408889634f

#define NXY  (BATCH * 32 * 16)     // 2048 xy blocks (32 ib x 16 jc)
#define NSYM (BATCH * 36 * 8)      // 1152 blocks per symmetric term
#define GRID_MAIN (NXY + 2 * NSYM) // 4352

// region stride: 4096 rows x 16 shorts
#define RSTRIDE 65536
// side: 0=xyz1/nor1 1=xyz2/nor2; form: 0=A 1=B; mat: 0=S 1=D
#define REG(side, form, mat, b) \
    (((((((side)*2 + (form))*2 + (mat))*BATCH) + (b))) * (size_t)RSTRIDE)
#define PARTIALS_OFF (32 * (size_t)RSTRIDE)   // shorts; = 4MB byte offset

// upper-triangle 8x8 supertile table: entry = (g<<4)|j5, g<=j5
__constant__ unsigned char SU_TBL[36] = {
    0x00,0x01,0x02,0x03,0x04,0x05,0x06,0x07,
    0x11,0x12,0x13,0x14,0x15,0x16,0x17,
    0x22,0x23,0x24,0x25,0x26,0x27,
    0x33,0x34,0x35,0x36,0x37,
    0x44,0x45,0x46,0x47,
    0x55,0x56,0x57,
    0x66,0x67,
    0x77
};

static __device__ __forceinline__ short f2bf(float f) {
    unsigned u = __builtin_bit_cast(unsigned, f);
    unsigned r = u + 0x7fffu + ((u >> 16) & 1u);   // RNE
    return (short)(r >> 16);
}
// v -> h (exact bf16 value) + l (residual)
static __device__ __forceinline__ void split(float v, float& h, float& l) {
    unsigned u = __builtin_bit_cast(unsigned, v);
    unsigned rb = (u + 0x7fffu + ((u >> 16) & 1u)) & 0xffff0000u;
    h = __builtin_bit_cast(float, rb);
    l = v - h;
}

// slot pairing (A,B): (gh,1)(gl,1)(1,g'h)(1,g'l), per dim (uh,vh)(uh,vl)(ul,vh)
// u = 2*log2e*xi, v = xj, g = -log2e*|x|^2  => accS = -log2e * S_ij
static __device__ __forceinline__ void encodeA(float x0, float x1, float x2,
                                               float n0, float n1, float n2,
                                               float fS[16], float fD[16]) {
    float s2 = fmaf(x2, x2, fmaf(x1, x1, x0 * x0));
    float gh, gl; split(-LOG2E * s2, gh, gl);
    float u0h,u0l,u1h,u1l,u2h,u2l;
    split(2.f*LOG2E*x0, u0h, u0l);
    split(2.f*LOG2E*x1, u1h, u1l);
    split(2.f*LOG2E*x2, u2h, u2l);
    fS[0]=gh;  fS[1]=gl;  fS[2]=1.f; fS[3]=1.f;
    fS[4]=u0h; fS[5]=u0h; fS[6]=u0l;
    fS[7]=u1h; fS[8]=u1h; fS[9]=u1l;
    fS[10]=u2h; fS[11]=u2h; fS[12]=u2l;
    fS[13]=0.f; fS[14]=0.f; fS[15]=0.f;
    float m0h,m0l,m1h,m1l,m2h,m2l;
    split(n0, m0h, m0l); split(n1, m1h, m1l); split(n2, m2h, m2l);
    fD[0]=m0h; fD[1]=m0h; fD[2]=m0l;
    fD[3]=m1h; fD[4]=m1h; fD[5]=m1l;
    fD[6]=m2h; fD[7]=m2h; fD[8]=m2l;
#pragma unroll
    for (int k = 9; k < 16; ++k) fD[k] = 0.f;
}

static __device__ __forceinline__ void encodeB(float x0, float x1, float x2,
                                               float n0, float n1, float n2,
                                               float fS[16], float fD[16]) {
    float s2 = fmaf(x2, x2, fmaf(x1, x1, x0 * x0));
    float gh, gl; split(-LOG2E * s2, gh, gl);
    float v0h,v0l,v1h,v1l,v2h,v2l;
    split(x0, v0h, v0l); split(x1, v1h, v1l); split(x2, v2h, v2l);
    fS[0]=1.f; fS[1]=1.f; fS[2]=gh;  fS[3]=gl;
    fS[4]=v0h; fS[5]=v0l; fS[6]=v0h;
    fS[7]=v1h; fS[8]=v1l; fS[9]=v1h;
    fS[10]=v2h; fS[11]=v2l; fS[12]=v2h;
    fS[13]=0.f; fS[14]=0.f; fS[15]=0.f;
    float m0h,m0l,m1h,m1l,m2h,m2l;
    split(n0, m0h, m0l); split(n1, m1h, m1l); split(n2, m2h, m2l);
    fD[0]=m0h; fD[1]=m0l; fD[2]=m0h;
    fD[3]=m1h; fD[4]=m1l; fD[5]=m1h;
    fD[6]=m2h; fD[7]=m2l; fD[8]=m2h;
#pragma unroll
    for (int k = 9; k < 16; ++k) fD[k] = 0.f;
}

// write 16 floats as bf16 into two lane-major 16B units u0 (k0-7), u0+32 (k8-15)
static __device__ __forceinline__ void store_units(short* base, int u0, const float f[16]) {
    bf16x8 a, b;
#pragma unroll
    for (int k = 0; k < 8; ++k) { a[k] = f2bf(f[k]); b[k] = f2bf(f[k + 8]); }
    *(bf16x8*)&base[(size_t)u0 * 8] = a;
    *(bf16x8*)&base[((size_t)u0 + 32) * 8] = b;
}

__global__ __launch_bounds__(256)
void vf_encode(const float* __restrict__ xyz1, const float* __restrict__ xyz2,
               const float* __restrict__ nor1, const float* __restrict__ nor2,
               short* __restrict__ ws)
{
    int gid = blockIdx.x * 256 + threadIdx.x;   // 2*4*4096 = 32768 total
    int side = gid >> 14;
    int b    = (gid >> 12) & 3;
    int j    = gid & 4095;

    const float* px = side ? xyz2 : xyz1;
    const float* pn = side ? nor2 : nor1;
    size_t off = ((size_t)b * NPTS + j) * 3;
    float x0 = px[off], x1 = px[off+1], x2 = px[off+2];
    float n0 = pn[off], n1 = pn[off+1], n2 = pn[off+2];

    float fS[16], fD[16];
    int u0 = (j >> 5) * 64 + (j & 31);

    encodeA(x0, x1, x2, n0, n1, n2, fS, fD);
    store_units(ws + REG(side, 0, 0, b), u0, fS);
    store_units(ws + REG(side, 0, 1, b), u0, fD);
    encodeB(x0, x1, x2, n0, n1, n2, fS, fD);
    store_units(ws + REG(side, 1, 0, b), u0, fS);
    store_units(ws + REG(side, 1, 1, b), u0, fD);
}

// epilogue for one 32x32 tile: 16 exp2 (trans) + packed mul/fma (VOP3P),
// 4 independent accumulator chains
static __device__ __forceinline__ void epi(const f32x16& aS, const f32x16& aD,
                                           f32x2& q0, f32x2& q1,
                                           f32x2& q2, f32x2& q3) {
#pragma unroll
    for (int e = 0; e < 16; e += 8) {
        f32x2 ex0, ex1, ex2, ex3, d0, d1, d2, d3;
        ex0[0] = __builtin_amdgcn_exp2f(aS[e+0]);
        ex0[1] = __builtin_amdgcn_exp2f(aS[e+1]);
        ex1[0] = __builtin_amdgcn_exp2f(aS[e+2]);
        ex1[1] = __builtin_amdgcn_exp2f(aS[e+3]);
        ex2[0] = __builtin_amdgcn_exp2f(aS[e+4]);
        ex2[1] = __builtin_amdgcn_exp2f(aS[e+5]);
        ex3[0] = __builtin_amdgcn_exp2f(aS[e+6]);
        ex3[1] = __builtin_amdgcn_exp2f(aS[e+7]);
        d0[0] = aD[e+0]; d0[1] = aD[e+1];
        d1[0] = aD[e+2]; d1[1] = aD[e+3];
        d2[0] = aD[e+4]; d2[1] = aD[e+5];
        d3[0] = aD[e+6]; d3[1] = aD[e+7];
        q0 = __builtin_elementwise_fma(ex0 * d0, d0, q0);   // v_pk_mul + v_pk_fma
        q1 = __builtin_elementwise_fma(ex1 * d1, d1, q1);
        q2 = __builtin_elementwise_fma(ex2 * d2, d2, q2);
        q3 = __builtin_elementwise_fma(ex3 * d3, d3, q3);
    }
}

__global__ __launch_bounds__(256)
void vf_main(short* __restrict__ ws)
{
    __shared__ short sBS[JCHUNK * 16];   // 8 KB
    __shared__ short sBD[JCHUNK * 16];   // 8 KB (total 16 KB)

    int blk = blockIdx.x;
    int term, b, ib, jc; float wgt;
    if (blk < NXY) {                         // xy: full grid
        term = 2; int r = blk;
        b = r & 3; r >>= 2;
        ib = r & 31; r >>= 5;
        jc = r;                              // 0..15
        wgt = -2.f;
    } else {                                 // xx / yy: upper-triangle supertiles
        int s = blk - NXY;
        term = (s < NSYM) ? 0 : 1;
        if (s >= NSYM) s -= NSYM;
        b = s & 3; s >>= 2;
        int sub = s & 7; s >>= 3;            // 4 ib x 2 jc within 512x512 su
        unsigned e = SU_TBL[s];
        int g = e >> 4, j5 = e & 15;
        ib = g * 4 + (sub & 3);
        jc = j5 * 2 + (sub >> 2);            // 0..15 (256-wide chunk)
        wgt = (g == j5) ? 1.f : 2.f;
    }

    int sideA = (term == 1) ? 1 : 0;
    int sideB = (term == 0) ? 0 : 1;

    const short* aSp = ws + REG(sideA, 0, 0, b);
    const short* aDp = ws + REG(sideA, 0, 1, b);
    const short* bSp = ws + REG(sideB, 1, 0, b) + (size_t)jc * 512 * 8;
    const short* bDp = ws + REG(sideB, 1, 1, b) + (size_t)jc * 512 * 8;

    const int tid  = threadIdx.x;
    const int lane = tid & 63;
    const int wv   = tid >> 6;

    // ---- stage B chunk: 512 16B units each for S and D, coalesced ----
#pragma unroll
    for (int k = 0; k < 2; ++k) {
        int ul = tid + k * 256;
        *(bf16x8*)&sBS[(size_t)ul * 8] = *(const bf16x8*)&bSp[(size_t)ul * 8];
        *(bf16x8*)&sBD[(size_t)ul * 8] = *(const bf16x8*)&bDp[(size_t)ul * 8];
    }

    // ---- A fragments: one 32-row i-tile per wave, lane-major 16B load ----
    int ua = (ib * 4 + wv) * 64 + lane;
    bf16x8 AS = *(const bf16x8*)&aSp[(size_t)ua * 8];
    bf16x8 AD = *(const bf16x8*)&aDp[(size_t)ua * 8];

    __syncthreads();

    f32x16 z;
#pragma unroll
    for (int k = 0; k < 16; ++k) z[k] = 0.f;

    f32x2 q0 = {0.f, 0.f}, q1 = {0.f, 0.f}, q2 = {0.f, 0.f}, q3 = {0.f, 0.f};

    // Software pipeline (depth 1): tile jt+1's MFMAs issue before tile jt's
    // epilogue, so MFMA latency hides under the ~200cyc trans epilogue.
    // Builtins keep the hazard bookkeeping correct (R7 lesson).
    bf16x8 BS = *(const bf16x8*)&sBS[(size_t)lane * 8];
    bf16x8 BD = *(const bf16x8*)&sBD[(size_t)lane * 8];
    f32x16 pS = __builtin_amdgcn_mfma_f32_32x32x16_bf16(AS, BS, z, 0, 0, 0);
    f32x16 pD = __builtin_amdgcn_mfma_f32_32x32x16_bf16(AD, BD, z, 0, 0, 0);

#pragma unroll
    for (int jt = 1; jt < JCHUNK / 32; ++jt) {
        int u = (jt * 64 + lane) * 8;
        bf16x8 nBS = *(const bf16x8*)&sBS[u];
        bf16x8 nBD = *(const bf16x8*)&sBD[u];
        f32x16 cS = __builtin_amdgcn_mfma_f32_32x32x16_bf16(AS, nBS, z, 0, 0, 0);
        f32x16 cD = __builtin_amdgcn_mfma_f32_32x32x16_bf16(AD, nBD, z, 0, 0, 0);
        epi(pS, pD, q0, q1, q2, q3);
        pS = cS; pD = cD;
    }
    epi(pS, pD, q0, q1, q2, q3);

    f32x2 qa = q0 + q1, qb = q2 + q3;
    float part = (qa[0] + qa[1]) + (qb[0] + qb[1]);
#pragma unroll
    for (int off = 32; off > 0; off >>= 1)
        part += __shfl_down(part, off, 64);

    // Cross-wave reduce through 16 reused bytes of sBS (no extra LDS).
    __syncthreads();                       // all waves done reading LDS tiles
    float* red = (float*)sBS;
    if (lane == 0) red[wv] = part;
    __syncthreads();
    if (tid == 0) {
        float s = (red[0] + red[1]) + (red[2] + red[3]);
        float* partials = (float*)(ws + PARTIALS_OFF);
        partials[blk] = wgt * s;           // plain store, distinct address
    }
}

__global__ __launch_bounds__(256)
void vf_reduce(const short* __restrict__ ws, float* __restrict__ out)
{
    const float* partials = (const float*)(ws + PARTIALS_OFF);
    int tid = threadIdx.x;
    double s = 0.0;
#pragma unroll
    for (int k = 0; k < (GRID_MAIN + 255) / 256; ++k) {
        int idx = tid + k * 256;
        if (idx < GRID_MAIN) s += (double)partials[idx];
    }
#pragma unroll
    for (int off = 32; off > 0; off >>= 1)
        s += __shfl_down(s, off, 64);
    __shared__ double red[4];
    int lane = tid & 63, wv = tid >> 6;
    if (lane == 0) red[wv] = s;
    __syncthreads();
    if (tid == 0)
        out[0] = (float)((red[0] + red[1]) + (red[2] + red[3]));
}

extern "C" void kernel_launch(void* const* d_in, const int* in_sizes, int n_in,
                              void* d_out, int out_size, void* d_ws, size_t ws_size,
                              hipStream_t stream) {
    const float* xyz1 = (const float*)d_in[0];
    const float* xyz2 = (const float*)d_in[1];
    const float* nor1 = (const float*)d_in[2];
    const float* nor2 = (const float*)d_in[3];
    float* out = (float*)d_out;
    short* ws  = (short*)d_ws;    // 4MB fragments + ~17.4KB partials

    vf_encode<<<(2 * BATCH * NPTS) / 256, 256, 0, stream>>>(xyz1, xyz2, nor1, nor2, ws);
    vf_main<<<GRID_MAIN, 256, 0, stream>>>(ws);
    vf_reduce<<<1, 256, 0, stream>>>(ws, out);
}

// Round 11
// 85.257 us; speedup vs baseline: 1.0403x; 1.0403x over previous
//
#include <hip/hip_runtime.h>

// Varifold loss kxx + kyy - 2*kxy via mfma_f32_32x32x16_bf16, three-phase.
// FINAL (R9 configuration -- best measured: 86.7us total, vf_main ~27us).
//
// Phase 1 (vf_encode): encode every point once into bf16 MFMA fragments in
//   d_ws (A-form and B-form, S and D matrices), hi/lo-split (~fp24), with
//   -log2(e) folded into S so accS IS the exp2 argument.
// Phase 2 (vf_main): builtin MFMA (R7: raw-asm MFMA -> hazard corruption).
//   Trans-pipe issue-bound: 16 v_exp_f32/tile x 16cyc/wave64 = 256 of ~356
//   issue cyc/tile (R8/R10 calibration; measured 74% issue efficiency).
//   xx/yy on upper-triangle 512x512 supertiles, off-diag weight 2 (70.8% of
//   pairs). Lane-major fragment layout -> conflict-free ds_read_b128.
//   No same-address atomics (R5: each = serialized ~10ns memory-side op;
//   12288 of them cost ~123us). Per-block plain store of partial.
// Phase 3 (vf_reduce): one block double-sums 2176 partials -> out[0].
//
// Failed levers (documented so nobody retries them): packed-f32 epilogue
// (R8, ~0), 8 blocks/CU occupancy (R8, ~0), VGPR cap (R9, -1.5us), SW
// pipeline depth 1 (R10, +2us regression), inline-asm MFMA (R7, corrupt).

typedef short bf16x8 __attribute__((ext_vector_type(8)));
typedef float f32x16 __attribute__((ext_vector_type(16)));
typedef float f32x2  __attribute__((ext_vector_type(2)));

#define NPTS 4096
#define BATCH 4
#define IBLK 128                   // 4 waves x one 32-row i-tile each
#define JCHUNK 512                 // 16 j-tiles of 32
#define LOG2E 1.4426950408889634f

#define NXY  (BATCH * 32 * 8)      // 1024 xy blocks (32 ib x 8 jc)
#define NSYM (BATCH * 36 * 4)      // 576 blocks per symmetric term
#define GRID_MAIN (NXY + 2 * NSYM) // 2176

// region stride: 4096 rows x 16 shorts
#define RSTRIDE 65536
// side: 0=xyz1/nor1 1=xyz2/nor2; form: 0=A 1=B; mat: 0=S 1=D
#define REG(side, form, mat, b) \
    (((((((side)*2 + (form))*2 + (mat))*BATCH) + (b))) * (size_t)RSTRIDE)
#define PARTIALS_OFF (32 * (size_t)RSTRIDE)   // shorts; = 4MB byte offset

// upper-triangle 8x8 supertile table: entry = (g<<4)|j5, g<=j5
__constant__ unsigned char SU_TBL[36] = {
    0x00,0x01,0x02,0x03,0x04,0x05,0x06,0x07,
    0x11,0x12,0x13,0x14,0x15,0x16,0x17,
    0x22,0x23,0x24,0x25,0x26,0x27,
    0x33,0x34,0x35,0x36,0x37,
    0x44,0x45,0x46,0x47,
    0x55,0x56,0x57,
    0x66,0x67,
    0x77
};

static __device__ __forceinline__ short f2bf(float f) {
    unsigned u = __builtin_bit_cast(unsigned, f);
    unsigned r = u + 0x7fffu + ((u >> 16) & 1u);   // RNE
    return (short)(r >> 16);
}
// v -> h (exact bf16 value) + l (residual)
static __device__ __forceinline__ void split(float v, float& h, float& l) {
    unsigned u = __builtin_bit_cast(unsigned, v);
    unsigned rb = (u + 0x7fffu + ((u >> 16) & 1u)) & 0xffff0000u;
    h = __builtin_bit_cast(float, rb);
    l = v - h;
}

// slot pairing (A,B): (gh,1)(gl,1)(1,g'h)(1,g'l), per dim (uh,vh)(uh,vl)(ul,vh)
// u = 2*log2e*xi, v = xj, g = -log2e*|x|^2  => accS = -log2e * S_ij
static __device__ __forceinline__ void encodeA(float x0, float x1, float x2,
                                               float n0, float n1, float n2,
                                               float fS[16], float fD[16]) {
    float s2 = fmaf(x2, x2, fmaf(x1, x1, x0 * x0));
    float gh, gl; split(-LOG2E * s2, gh, gl);
    float u0h,u0l,u1h,u1l,u2h,u2l;
    split(2.f*LOG2E*x0, u0h, u0l);
    split(2.f*LOG2E*x1, u1h, u1l);
    split(2.f*LOG2E*x2, u2h, u2l);
    fS[0]=gh;  fS[1]=gl;  fS[2]=1.f; fS[3]=1.f;
    fS[4]=u0h; fS[5]=u0h; fS[6]=u0l;
    fS[7]=u1h; fS[8]=u1h; fS[9]=u1l;
    fS[10]=u2h; fS[11]=u2h; fS[12]=u2l;
    fS[13]=0.f; fS[14]=0.f; fS[15]=0.f;
    float m0h,m0l,m1h,m1l,m2h,m2l;
    split(n0, m0h, m0l); split(n1, m1h, m1l); split(n2, m2h, m2l);
    fD[0]=m0h; fD[1]=m0h; fD[2]=m0l;
    fD[3]=m1h; fD[4]=m1h; fD[5]=m1l;
    fD[6]=m2h; fD[7]=m2h; fD[8]=m2l;
#pragma unroll
    for (int k = 9; k < 16; ++k) fD[k] = 0.f;
}

static __device__ __forceinline__ void encodeB(float x0, float x1, float x2,
                                               float n0, float n1, float n2,
                                               float fS[16], float fD[16]) {
    float s2 = fmaf(x2, x2, fmaf(x1, x1, x0 * x0));
    float gh, gl; split(-LOG2E * s2, gh, gl);
    float v0h,v0l,v1h,v1l,v2h,v2l;
    split(x0, v0h, v0l); split(x1, v1h, v1l); split(x2, v2h, v2l);
    fS[0]=1.f; fS[1]=1.f; fS[2]=gh;  fS[3]=gl;
    fS[4]=v0h; fS[5]=v0l; fS[6]=v0h;
    fS[7]=v1h; fS[8]=v1l; fS[9]=v1h;
    fS[10]=v2h; fS[11]=v2l; fS[12]=v2h;
    fS[13]=0.f; fS[14]=0.f; fS[15]=0.f;
    float m0h,m0l,m1h,m1l,m2h,m2l;
    split(n0, m0h, m0l); split(n1, m1h, m1l); split(n2, m2h, m2l);
    fD[0]=m0h; fD[1]=m0l; fD[2]=m0h;
    fD[3]=m1h; fD[4]=m1l; fD[5]=m1h;
    fD[6]=m2h; fD[7]=m2l; fD[8]=m2h;
#pragma unroll
    for (int k = 9; k < 16; ++k) fD[k] = 0.f;
}

// write 16 floats as bf16 into two lane-major 16B units u0 (k0-7), u0+32 (k8-15)
static __device__ __forceinline__ void store_units(short* base, int u0, const float f[16]) {
    bf16x8 a, b;
#pragma unroll
    for (int k = 0; k < 8; ++k) { a[k] = f2bf(f[k]); b[k] = f2bf(f[k + 8]); }
    *(bf16x8*)&base[(size_t)u0 * 8] = a;
    *(bf16x8*)&base[((size_t)u0 + 32) * 8] = b;
}

__global__ __launch_bounds__(256)
void vf_encode(const float* __restrict__ xyz1, const float* __restrict__ xyz2,
               const float* __restrict__ nor1, const float* __restrict__ nor2,
               short* __restrict__ ws)
{
    int gid = blockIdx.x * 256 + threadIdx.x;   // 2*4*4096 = 32768 total
    int side = gid >> 14;
    int b    = (gid >> 12) & 3;
    int j    = gid & 4095;

    const float* px = side ? xyz2 : xyz1;
    const float* pn = side ? nor2 : nor1;
    size_t off = ((size_t)b * NPTS + j) * 3;
    float x0 = px[off], x1 = px[off+1], x2 = px[off+2];
    float n0 = pn[off], n1 = pn[off+1], n2 = pn[off+2];

    float fS[16], fD[16];
    int u0 = (j >> 5) * 64 + (j & 31);

    encodeA(x0, x1, x2, n0, n1, n2, fS, fD);
    store_units(ws + REG(side, 0, 0, b), u0, fS);
    store_units(ws + REG(side, 0, 1, b), u0, fD);
    encodeB(x0, x1, x2, n0, n1, n2, fS, fD);
    store_units(ws + REG(side, 1, 0, b), u0, fS);
    store_units(ws + REG(side, 1, 1, b), u0, fD);
}

// epilogue for one 32x32 tile: 16 exp2 (trans) + packed mul/fma (VOP3P)
static __device__ __forceinline__ void epi(const f32x16& aS, const f32x16& aD,
                                           f32x2& q0, f32x2& q1) {
#pragma unroll
    for (int e = 0; e < 16; e += 4) {
        f32x2 ex0, ex1, d0, d1;
        ex0[0] = __builtin_amdgcn_exp2f(aS[e+0]);
        ex0[1] = __builtin_amdgcn_exp2f(aS[e+1]);
        ex1[0] = __builtin_amdgcn_exp2f(aS[e+2]);
        ex1[1] = __builtin_amdgcn_exp2f(aS[e+3]);
        d0[0] = aD[e+0]; d0[1] = aD[e+1];
        d1[0] = aD[e+2]; d1[1] = aD[e+3];
        q0 = __builtin_elementwise_fma(ex0 * d0, d0, q0);   // v_pk_mul + v_pk_fma
        q1 = __builtin_elementwise_fma(ex1 * d1, d1, q1);
    }
}

__global__ __launch_bounds__(256, 4)   // 128 VGPR cap: room for VGPR-form accs
void vf_main(short* __restrict__ ws)
{
    __shared__ short sBS[JCHUNK * 16];   // 16 KB
    __shared__ short sBD[JCHUNK * 16];   // 16 KB

    int blk = blockIdx.x;
    int term, b, ib, jc; float wgt;
    if (blk < NXY) {                         // xy: full grid
        term = 2; int r = blk;
        b = r & 3; r >>= 2;
        ib = r & 31; r >>= 5;
        jc = r;                              // 0..7
        wgt = -2.f;
    } else {                                 // xx / yy: upper-triangle supertiles
        int s = blk - NXY;
        term = (s < NSYM) ? 0 : 1;
        if (s >= NSYM) s -= NSYM;
        b = s & 3; s >>= 2;
        int sub = s & 3; s >>= 2;            // ib within 512-row supertile
        unsigned e = SU_TBL[s];
        int g = e >> 4, j5 = e & 15;
        ib = g * 4 + sub;
        jc = j5;                             // 0..7 (512-wide chunk)
        wgt = (g == j5) ? 1.f : 2.f;
    }

    int sideA = (term == 1) ? 1 : 0;
    int sideB = (term == 0) ? 0 : 1;

    const short* aSp = ws + REG(sideA, 0, 0, b);
    const short* aDp = ws + REG(sideA, 0, 1, b);
    const short* bSp = ws + REG(sideB, 1, 0, b) + (size_t)jc * 1024 * 8;
    const short* bDp = ws + REG(sideB, 1, 1, b) + (size_t)jc * 1024 * 8;

    const int tid  = threadIdx.x;
    const int lane = tid & 63;
    const int wv   = tid >> 6;

    // ---- stage B chunk: 1024 16B units each for S and D, coalesced ----
#pragma unroll
    for (int k = 0; k < 4; ++k) {
        int ul = tid + k * 256;
        *(bf16x8*)&sBS[(size_t)ul * 8] = *(const bf16x8*)&bSp[(size_t)ul * 8];
        *(bf16x8*)&sBD[(size_t)ul * 8] = *(const bf16x8*)&bDp[(size_t)ul * 8];
    }

    // ---- A fragments: one 32-row i-tile per wave, lane-major 16B load ----
    int ua = (ib * 4 + wv) * 64 + lane;
    bf16x8 AS = *(const bf16x8*)&aSp[(size_t)ua * 8];
    bf16x8 AD = *(const bf16x8*)&aDp[(size_t)ua * 8];

    __syncthreads();

    f32x16 z;
#pragma unroll
    for (int k = 0; k < 16; ++k) z[k] = 0.f;

    f32x2 q0 = {0.f, 0.f}, q1 = {0.f, 0.f};

#pragma unroll
    for (int jt = 0; jt < JCHUNK / 32; ++jt) {
        int u = (jt * 64 + lane) * 8;
        bf16x8 BS = *(const bf16x8*)&sBS[u];
        bf16x8 BD = *(const bf16x8*)&sBD[u];
        f32x16 aSacc = __builtin_amdgcn_mfma_f32_32x32x16_bf16(AS, BS, z, 0, 0, 0);
        f32x16 aDacc = __builtin_amdgcn_mfma_f32_32x32x16_bf16(AD, BD, z, 0, 0, 0);
        epi(aSacc, aDacc, q0, q1);
    }

    float part = (q0[0] + q0[1]) + (q1[0] + q1[1]);
#pragma unroll
    for (int off = 32; off > 0; off >>= 1)
        part += __shfl_down(part, off, 64);

    // Cross-wave reduce through 16 reused bytes of sBS (no extra LDS).
    __syncthreads();                       // all waves done reading LDS tiles
    float* red = (float*)sBS;
    if (lane == 0) red[wv] = part;
    __syncthreads();
    if (tid == 0) {
        float s = (red[0] + red[1]) + (red[2] + red[3]);
        float* partials = (float*)(ws + PARTIALS_OFF);
        partials[blk] = wgt * s;           // plain store, distinct address
    }
}

__global__ __launch_bounds__(256)
void vf_reduce(const short* __restrict__ ws, float* __restrict__ out)
{
    const float* partials = (const float*)(ws + PARTIALS_OFF);
    int tid = threadIdx.x;
    double s = 0.0;
#pragma unroll
    for (int k = 0; k < (GRID_MAIN + 255) / 256; ++k) {
        int idx = tid + k * 256;
        if (idx < GRID_MAIN) s += (double)partials[idx];
    }
#pragma unroll
    for (int off = 32; off > 0; off >>= 1)
        s += __shfl_down(s, off, 64);
    __shared__ double red[4];
    int lane = tid & 63, wv = tid >> 6;
    if (lane == 0) red[wv] = s;
    __syncthreads();
    if (tid == 0)
        out[0] = (float)((red[0] + red[1]) + (red[2] + red[3]));
}

extern "C" void kernel_launch(void* const* d_in, const int* in_sizes, int n_in,
                              void* d_out, int out_size, void* d_ws, size_t ws_size,
                              hipStream_t stream) {
    const float* xyz1 = (const float*)d_in[0];
    const float* xyz2 = (const float*)d_in[1];
    const float* nor1 = (const float*)d_in[2];
    const float* nor2 = (const float*)d_in[3];
    float* out = (float*)d_out;
    short* ws  = (short*)d_ws;    // 4MB fragments + ~8.7KB partials

    vf_encode<<<(2 * BATCH * NPTS) / 256, 256, 0, stream>>>(xyz1, xyz2, nor1, nor2, ws);
    vf_main<<<GRID_MAIN, 256, 0, stream>>>(ws);
    vf_reduce<<<1, 256, 0, stream>>>(ws, out);
}